// Round 4
// baseline (64.248 us; speedup 1.0000x reference)
//
#include <hip/hip_runtime.h>

// SigmoidDVHLoss: per-(batch,label) mean of sigmoid((dose-thr)/0.1) for pred
// and target, then MSE over the 8x3 DVH entries.
//
// loss = mean_{b,k} ( (sum_{m==k}(sig_p - sig_t)) / count_k )^2
//
// R3: R2's hoisted loads compiled to VGPR=28 -> compiler re-serialized them.
// Force all 12 global_load_dwordx4 to issue before any compute with
// __builtin_amdgcn_sched_barrier(0) (nothing may cross), giving 12
// outstanding loads/thread for latency hiding.

#define NB 8
#define NK 3
#define VPB (1 << 21)        // 128^3 voxels per batch
#define BLOCK 256
#define CHUNKS 512           // blocks per batch
#define VOX_PER_BLOCK (VPB / CHUNKS)   // 4096 voxels = 1024 float4

// ws layout (doubles): [0..23] sum_diff[b*3+k], [24..47] count[b*3+k]
#define WS_DOUBLES 48

#define LOG2E_X10 14.4269504088896341f   // 10 / ln(2)

__global__ __launch_bounds__(BLOCK) void dvh_sum_kernel(
    const float* __restrict__ pred,
    const float* __restrict__ targ,
    const int*   __restrict__ mask,
    const float* __restrict__ ptv,
    double*      __restrict__ ws)
{
    const int batch = blockIdx.x / CHUNKS;
    const int chunk = blockIdx.x % CHUNKS;
    const long base = (long)batch * VPB + (long)chunk * VOX_PER_BLOCK;

    const float4* __restrict__ p4 = (const float4*)(pred + base);
    const float4* __restrict__ t4 = (const float4*)(targ + base);
    const int4*   __restrict__ m4 = (const int4*)(mask + base);

    const int tid = threadIdx.x;

    // ---- issue all 12 loads; nothing may be scheduled across the fence ----
    float4 p0 = p4[tid];
    float4 p1 = p4[tid + BLOCK];
    float4 p2 = p4[tid + 2 * BLOCK];
    float4 p3 = p4[tid + 3 * BLOCK];
    float4 t0 = t4[tid];
    float4 t1 = t4[tid + BLOCK];
    float4 t2 = t4[tid + 2 * BLOCK];
    float4 t3 = t4[tid + 3 * BLOCK];
    int4   m0 = m4[tid];
    int4   m1 = m4[tid + BLOCK];
    int4   m2 = m4[tid + 2 * BLOCK];
    int4   m3 = m4[tid + 3 * BLOCK];
    __builtin_amdgcn_sched_barrier(0);

    // scaled thresholds: sig = rcp(1 + 2^(thr*C - d*C))
    const float tc0 = ptv[0] * LOG2E_X10;
    const float tc1 = ptv[1] * LOG2E_X10;
    const float tc2 = ptv[2] * LOG2E_X10;

    float d0 = 0.f, d1 = 0.f, d2 = 0.f;   // sum of (sig_p - sig_t) per label
    int   c0 = 0,   c1 = 0,   c2 = 0;     // counts per label

    #define DO_ELEM(PJ, TJ, MJ)                                          \
    {                                                                    \
        const int mm = (MJ);                                             \
        const bool is1 = (mm == 1), is2 = (mm == 2), is3 = (mm == 3);    \
        const float thrC = is1 ? tc0 : (is2 ? tc1 : tc2);                \
        const float ep = __builtin_amdgcn_exp2f(                         \
                             __builtin_fmaf((PJ), -LOG2E_X10, thrC));    \
        const float et = __builtin_amdgcn_exp2f(                         \
                             __builtin_fmaf((TJ), -LOG2E_X10, thrC));    \
        const float sgp = __builtin_amdgcn_rcpf(1.0f + ep);              \
        const float sgt = __builtin_amdgcn_rcpf(1.0f + et);              \
        const float df  = sgp - sgt;                                     \
        d0 += is1 ? df : 0.0f;                                           \
        d1 += is2 ? df : 0.0f;                                           \
        d2 += is3 ? df : 0.0f;                                           \
        c0 += is1 ? 1 : 0;                                               \
        c1 += is2 ? 1 : 0;                                               \
        c2 += is3 ? 1 : 0;                                               \
    }

    #define DO_VEC4(P, T, M)                                             \
        DO_ELEM(P.x, T.x, M.x)                                           \
        DO_ELEM(P.y, T.y, M.y)                                           \
        DO_ELEM(P.z, T.z, M.z)                                           \
        DO_ELEM(P.w, T.w, M.w)

    DO_VEC4(p0, t0, m0)
    DO_VEC4(p1, t1, m1)
    DO_VEC4(p2, t2, m2)
    DO_VEC4(p3, t3, m3)
    #undef DO_VEC4
    #undef DO_ELEM

    // promote to double, wave(64)-reduce, then LDS across the 4 waves
    double v[6] = { (double)d0, (double)d1, (double)d2,
                    (double)c0, (double)c1, (double)c2 };

    #pragma unroll
    for (int q = 0; q < 6; ++q) {
        double x = v[q];
        #pragma unroll
        for (int off = 32; off > 0; off >>= 1)
            x += __shfl_down(x, off, 64);
        v[q] = x;
    }

    __shared__ double red[BLOCK / 64][6];
    const int wid  = threadIdx.x >> 6;
    const int lane = threadIdx.x & 63;
    if (lane == 0) {
        #pragma unroll
        for (int q = 0; q < 6; ++q) red[wid][q] = v[q];
    }
    __syncthreads();

    if (threadIdx.x < 6) {
        const int q = threadIdx.x;
        double s = red[0][q] + red[1][q] + red[2][q] + red[3][q];
        const int k   = q % 3;
        const int arr = q / 3;           // 0 = sum_diff, 1 = count
        atomicAdd(&ws[arr * (NB * NK) + batch * NK + k], s);
    }
}

__global__ __launch_bounds__(64) void dvh_finalize_kernel(
    const double* __restrict__ ws, float* __restrict__ out)
{
    const int i = threadIdx.x;
    double v = 0.0;
    if (i < NB * NK) {
        double sd = ws[i];
        double c  = ws[NB * NK + i];
        double d  = sd / c;
        v = d * d;
    }
    #pragma unroll
    for (int off = 32; off > 0; off >>= 1)
        v += __shfl_down(v, off, 64);
    if (i == 0) out[0] = (float)(v / (double)(NB * NK));
}

extern "C" void kernel_launch(void* const* d_in, const int* in_sizes, int n_in,
                              void* d_out, int out_size, void* d_ws, size_t ws_size,
                              hipStream_t stream) {
    const float* pred = (const float*)d_in[0];
    const float* targ = (const float*)d_in[1];
    const int*   mask = (const int*)d_in[2];
    const float* ptv  = (const float*)d_in[3];
    float* out = (float*)d_out;
    double* ws = (double*)d_ws;

    hipMemsetAsync(ws, 0, WS_DOUBLES * sizeof(double), stream);

    dvh_sum_kernel<<<NB * CHUNKS, BLOCK, 0, stream>>>(pred, targ, mask, ptv, ws);
    dvh_finalize_kernel<<<1, 64, 0, stream>>>(ws, out);
}

// Round 5
// 62.922 us; speedup vs baseline: 1.0211x; 1.0211x over previous
//
#include <hip/hip_runtime.h>

// SigmoidDVHLoss: per-(batch,label) mean of sigmoid((dose-thr)/0.1) for pred
// and target, then MSE over the 8x3 DVH entries.
//
// loss = mean_{b,k} ( (sum_{m==k}(sig_p - sig_t)) / count_k )^2
//
// R4: R2 (source hoist) and R3 (sched_barrier) both failed to create MLP —
// VGPR stayed 28, loads re-serialized by RA. Force it: ONE inline-asm block
// issues all 12 global_load_dwordx4 (saddr + 32-bit voffset) back-to-back,
// single s_waitcnt vmcnt(0). Early-clobber outputs pin 48 data VGPRs live.

#define NB 8
#define NK 3
#define VPB (1 << 21)        // 128^3 voxels per batch
#define BLOCK 256
#define CHUNKS 512           // blocks per batch
#define VOX_PER_BLOCK (VPB / CHUNKS)   // 4096 voxels = 1024 float4

// ws layout (doubles): [0..23] sum_diff[b*3+k], [24..47] count[b*3+k]
#define WS_DOUBLES 48

#define LOG2E_X10 14.4269504088896341f   // 10 / ln(2)

typedef float v4f __attribute__((ext_vector_type(4)));
typedef int   v4i __attribute__((ext_vector_type(4)));

__global__ __launch_bounds__(BLOCK) void dvh_sum_kernel(
    const float* __restrict__ pred,
    const float* __restrict__ targ,
    const int*   __restrict__ mask,
    const float* __restrict__ ptv,
    double*      __restrict__ ws)
{
    const int batch = blockIdx.x / CHUNKS;
    const int chunk = blockIdx.x % CHUNKS;
    const long base = (long)batch * VPB + (long)chunk * VOX_PER_BLOCK;

    const float* predb = pred + base;   // uniform -> SGPR pair
    const float* targb = targ + base;
    const int*   maskb = mask + base;

    const int tid = threadIdx.x;
    const unsigned off0 = (unsigned)(tid) * 16u;
    const unsigned off1 = (unsigned)(tid + BLOCK) * 16u;
    const unsigned off2 = (unsigned)(tid + 2 * BLOCK) * 16u;
    const unsigned off3 = (unsigned)(tid + 3 * BLOCK) * 16u;

    v4f P0, P1, P2, P3, T0, T1, T2, T3;
    v4i M0, M1, M2, M3;

    // ---- all 12 loads issued back-to-back, ONE wait: 12 outstanding/thread.
    asm volatile(
        "global_load_dwordx4 %0,  %12, %16\n\t"
        "global_load_dwordx4 %1,  %13, %16\n\t"
        "global_load_dwordx4 %2,  %14, %16\n\t"
        "global_load_dwordx4 %3,  %15, %16\n\t"
        "global_load_dwordx4 %4,  %12, %17\n\t"
        "global_load_dwordx4 %5,  %13, %17\n\t"
        "global_load_dwordx4 %6,  %14, %17\n\t"
        "global_load_dwordx4 %7,  %15, %17\n\t"
        "global_load_dwordx4 %8,  %12, %18\n\t"
        "global_load_dwordx4 %9,  %13, %18\n\t"
        "global_load_dwordx4 %10, %14, %18\n\t"
        "global_load_dwordx4 %11, %15, %18\n\t"
        "s_waitcnt vmcnt(0)"
        : "=&v"(P0), "=&v"(P1), "=&v"(P2), "=&v"(P3),
          "=&v"(T0), "=&v"(T1), "=&v"(T2), "=&v"(T3),
          "=&v"(M0), "=&v"(M1), "=&v"(M2), "=&v"(M3)
        : "v"(off0), "v"(off1), "v"(off2), "v"(off3),
          "s"(predb), "s"(targb), "s"(maskb));

    // scaled thresholds: sig = rcp(1 + 2^(thr*C - d*C))
    const float tc0 = ptv[0] * LOG2E_X10;
    const float tc1 = ptv[1] * LOG2E_X10;
    const float tc2 = ptv[2] * LOG2E_X10;

    float d0 = 0.f, d1 = 0.f, d2 = 0.f;   // sum of (sig_p - sig_t) per label
    int   c0 = 0,   c1 = 0,   c2 = 0;     // counts per label

    #define DO_ELEM(PJ, TJ, MJ)                                          \
    {                                                                    \
        const int mm = (MJ);                                             \
        const bool is1 = (mm == 1), is2 = (mm == 2), is3 = (mm == 3);    \
        const float thrC = is1 ? tc0 : (is2 ? tc1 : tc2);                \
        const float ep = __builtin_amdgcn_exp2f(                         \
                             __builtin_fmaf((PJ), -LOG2E_X10, thrC));    \
        const float et = __builtin_amdgcn_exp2f(                         \
                             __builtin_fmaf((TJ), -LOG2E_X10, thrC));    \
        const float sgp = __builtin_amdgcn_rcpf(1.0f + ep);              \
        const float sgt = __builtin_amdgcn_rcpf(1.0f + et);              \
        const float df  = sgp - sgt;                                     \
        d0 += is1 ? df : 0.0f;                                           \
        d1 += is2 ? df : 0.0f;                                           \
        d2 += is3 ? df : 0.0f;                                           \
        c0 += is1 ? 1 : 0;                                               \
        c1 += is2 ? 1 : 0;                                               \
        c2 += is3 ? 1 : 0;                                               \
    }

    #define DO_VEC4(P, T, M)                                             \
        DO_ELEM(P[0], T[0], M[0])                                        \
        DO_ELEM(P[1], T[1], M[1])                                        \
        DO_ELEM(P[2], T[2], M[2])                                        \
        DO_ELEM(P[3], T[3], M[3])

    DO_VEC4(P0, T0, M0)
    DO_VEC4(P1, T1, M1)
    DO_VEC4(P2, T2, M2)
    DO_VEC4(P3, T3, M3)
    #undef DO_VEC4
    #undef DO_ELEM

    // promote to double, wave(64)-reduce, then LDS across the 4 waves
    double v[6] = { (double)d0, (double)d1, (double)d2,
                    (double)c0, (double)c1, (double)c2 };

    #pragma unroll
    for (int q = 0; q < 6; ++q) {
        double x = v[q];
        #pragma unroll
        for (int off = 32; off > 0; off >>= 1)
            x += __shfl_down(x, off, 64);
        v[q] = x;
    }

    __shared__ double red[BLOCK / 64][6];
    const int wid  = threadIdx.x >> 6;
    const int lane = threadIdx.x & 63;
    if (lane == 0) {
        #pragma unroll
        for (int q = 0; q < 6; ++q) red[wid][q] = v[q];
    }
    __syncthreads();

    if (threadIdx.x < 6) {
        const int q = threadIdx.x;
        double s = red[0][q] + red[1][q] + red[2][q] + red[3][q];
        const int k   = q % 3;
        const int arr = q / 3;           // 0 = sum_diff, 1 = count
        atomicAdd(&ws[arr * (NB * NK) + batch * NK + k], s);
    }
}

__global__ __launch_bounds__(64) void dvh_finalize_kernel(
    const double* __restrict__ ws, float* __restrict__ out)
{
    const int i = threadIdx.x;
    double v = 0.0;
    if (i < NB * NK) {
        double sd = ws[i];
        double c  = ws[NB * NK + i];
        double d  = sd / c;
        v = d * d;
    }
    #pragma unroll
    for (int off = 32; off > 0; off >>= 1)
        v += __shfl_down(v, off, 64);
    if (i == 0) out[0] = (float)(v / (double)(NB * NK));
}

extern "C" void kernel_launch(void* const* d_in, const int* in_sizes, int n_in,
                              void* d_out, int out_size, void* d_ws, size_t ws_size,
                              hipStream_t stream) {
    const float* pred = (const float*)d_in[0];
    const float* targ = (const float*)d_in[1];
    const int*   mask = (const int*)d_in[2];
    const float* ptv  = (const float*)d_in[3];
    float* out = (float*)d_out;
    double* ws = (double*)d_ws;

    hipMemsetAsync(ws, 0, WS_DOUBLES * sizeof(double), stream);

    dvh_sum_kernel<<<NB * CHUNKS, BLOCK, 0, stream>>>(pred, targ, mask, ptv, ws);
    dvh_finalize_kernel<<<1, 64, 0, stream>>>(ws, out);
}

// Round 6
// 41.471 us; speedup vs baseline: 1.5492x; 1.5172x over previous
//
#include <hip/hip_runtime.h>

// SigmoidDVHLoss: per-(batch,label) mean of sigmoid((dose-thr)/0.1) for pred
// and target, then MSE over the 8x3 DVH entries.
//
// loss = mean_{b,k} ( (sum_{m==k}(sig_p - sig_t)) / count_k )^2
//
// R5: R1-R4 all flat at ~70us with nothing saturated -> the constant across
// all rounds was the epilogue: 24576 global f64 atomicAdds onto 48 doubles
// (3 cache lines) from 8 XCDs = serialized same-line atomic service.
// Remove ALL global atomics: stage1 stores per-block partials (SoA),
// a 24-block kernel reduces per-(b,k), a 1-wave kernel emits the scalar.

#define NB 8
#define NK 3
#define VPB (1 << 21)        // 128^3 voxels per batch
#define BLOCK 256
#define CHUNKS 512           // blocks per batch
#define NBLOCKS (NB * CHUNKS)            // 4096
#define VOX_PER_BLOCK (VPB / CHUNKS)     // 4096 voxels = 1024 float4

// ws layout (doubles):
//   [q * NBLOCKS + block], q = 0..2 : sum_diff for k=q
//   [q * NBLOCKS + block], q = 3..5 : count    for k=q-3
//   ws2 = ws + 6*NBLOCKS : 24 doubles, per-(b,k) squared DVH diff
#define WS_PARTIALS (6 * NBLOCKS)

#define LOG2E_X10 14.4269504088896341f   // 10 / ln(2)

typedef float v4f __attribute__((ext_vector_type(4)));
typedef int   v4i __attribute__((ext_vector_type(4)));

__global__ __launch_bounds__(BLOCK) void dvh_sum_kernel(
    const float* __restrict__ pred,
    const float* __restrict__ targ,
    const int*   __restrict__ mask,
    const float* __restrict__ ptv,
    double*      __restrict__ ws)
{
    const int bid   = blockIdx.x;
    const int batch = bid / CHUNKS;
    const int chunk = bid % CHUNKS;
    const long base = (long)batch * VPB + (long)chunk * VOX_PER_BLOCK;

    const float* predb = pred + base;   // uniform -> SGPR pair
    const float* targb = targ + base;
    const int*   maskb = mask + base;

    const int tid = threadIdx.x;
    const unsigned off0 = (unsigned)(tid) * 16u;
    const unsigned off1 = (unsigned)(tid + BLOCK) * 16u;
    const unsigned off2 = (unsigned)(tid + 2 * BLOCK) * 16u;
    const unsigned off3 = (unsigned)(tid + 3 * BLOCK) * 16u;

    v4f P0, P1, P2, P3, T0, T1, T2, T3;
    v4i M0, M1, M2, M3;

    // all 12 loads issued back-to-back, one wait: 12 outstanding/thread
    asm volatile(
        "global_load_dwordx4 %0,  %12, %16\n\t"
        "global_load_dwordx4 %1,  %13, %16\n\t"
        "global_load_dwordx4 %2,  %14, %16\n\t"
        "global_load_dwordx4 %3,  %15, %16\n\t"
        "global_load_dwordx4 %4,  %12, %17\n\t"
        "global_load_dwordx4 %5,  %13, %17\n\t"
        "global_load_dwordx4 %6,  %14, %17\n\t"
        "global_load_dwordx4 %7,  %15, %17\n\t"
        "global_load_dwordx4 %8,  %12, %18\n\t"
        "global_load_dwordx4 %9,  %13, %18\n\t"
        "global_load_dwordx4 %10, %14, %18\n\t"
        "global_load_dwordx4 %11, %15, %18\n\t"
        "s_waitcnt vmcnt(0)"
        : "=&v"(P0), "=&v"(P1), "=&v"(P2), "=&v"(P3),
          "=&v"(T0), "=&v"(T1), "=&v"(T2), "=&v"(T3),
          "=&v"(M0), "=&v"(M1), "=&v"(M2), "=&v"(M3)
        : "v"(off0), "v"(off1), "v"(off2), "v"(off3),
          "s"(predb), "s"(targb), "s"(maskb));

    // scaled thresholds: sig = rcp(1 + 2^(thr*C - d*C))
    const float tc0 = ptv[0] * LOG2E_X10;
    const float tc1 = ptv[1] * LOG2E_X10;
    const float tc2 = ptv[2] * LOG2E_X10;

    float d0 = 0.f, d1 = 0.f, d2 = 0.f;   // sum of (sig_p - sig_t) per label
    int   c0 = 0,   c1 = 0,   c2 = 0;     // counts per label

    #define DO_ELEM(PJ, TJ, MJ)                                          \
    {                                                                    \
        const int mm = (MJ);                                             \
        const bool is1 = (mm == 1), is2 = (mm == 2), is3 = (mm == 3);    \
        const float thrC = is1 ? tc0 : (is2 ? tc1 : tc2);                \
        const float ep = __builtin_amdgcn_exp2f(                         \
                             __builtin_fmaf((PJ), -LOG2E_X10, thrC));    \
        const float et = __builtin_amdgcn_exp2f(                         \
                             __builtin_fmaf((TJ), -LOG2E_X10, thrC));    \
        const float sgp = __builtin_amdgcn_rcpf(1.0f + ep);              \
        const float sgt = __builtin_amdgcn_rcpf(1.0f + et);              \
        const float df  = sgp - sgt;                                     \
        d0 += is1 ? df : 0.0f;                                           \
        d1 += is2 ? df : 0.0f;                                           \
        d2 += is3 ? df : 0.0f;                                           \
        c0 += is1 ? 1 : 0;                                               \
        c1 += is2 ? 1 : 0;                                               \
        c2 += is3 ? 1 : 0;                                               \
    }

    #define DO_VEC4(P, T, M)                                             \
        DO_ELEM(P[0], T[0], M[0])                                        \
        DO_ELEM(P[1], T[1], M[1])                                        \
        DO_ELEM(P[2], T[2], M[2])                                        \
        DO_ELEM(P[3], T[3], M[3])

    DO_VEC4(P0, T0, M0)
    DO_VEC4(P1, T1, M1)
    DO_VEC4(P2, T2, M2)
    DO_VEC4(P3, T3, M3)
    #undef DO_VEC4
    #undef DO_ELEM

    // wave(64) butterfly reduce: f32 for diffs, int for counts
    #pragma unroll
    for (int off = 32; off > 0; off >>= 1) {
        d0 += __shfl_down(d0, off, 64);
        d1 += __shfl_down(d1, off, 64);
        d2 += __shfl_down(d2, off, 64);
        c0 += __shfl_down(c0, off, 64);
        c1 += __shfl_down(c1, off, 64);
        c2 += __shfl_down(c2, off, 64);
    }

    __shared__ double redd[BLOCK / 64][3];
    __shared__ int    redc[BLOCK / 64][3];
    const int wid  = threadIdx.x >> 6;
    const int lane = threadIdx.x & 63;
    if (lane == 0) {
        redd[wid][0] = (double)d0; redd[wid][1] = (double)d1; redd[wid][2] = (double)d2;
        redc[wid][0] = c0;         redc[wid][1] = c1;         redc[wid][2] = c2;
    }
    __syncthreads();

    if (threadIdx.x < 6) {
        const int q = threadIdx.x;           // 0..2 diff, 3..5 count
        double s;
        if (q < 3)
            s = redd[0][q] + redd[1][q] + redd[2][q] + redd[3][q];
        else
            s = (double)(redc[0][q - 3] + redc[1][q - 3] + redc[2][q - 3] + redc[3][q - 3]);
        ws[(size_t)q * NBLOCKS + bid] = s;   // plain store — no atomics
    }
}

// One block per (b,k): reduce 512 diff partials + 512 count partials.
__global__ __launch_bounds__(64) void dvh_reduce_kernel(
    const double* __restrict__ ws, double* __restrict__ ws2)
{
    const int j = blockIdx.x;            // 0..23
    const int b = j / NK, k = j % NK;
    const double* dp = ws + (size_t)k * NBLOCKS + b * CHUNKS;
    const double* cp = ws + (size_t)(NK + k) * NBLOCKS + b * CHUNKS;

    double sd = 0.0, sc = 0.0;
    #pragma unroll
    for (int i = threadIdx.x; i < CHUNKS; i += 64) {
        sd += dp[i];
        sc += cp[i];
    }
    #pragma unroll
    for (int off = 32; off > 0; off >>= 1) {
        sd += __shfl_down(sd, off, 64);
        sc += __shfl_down(sc, off, 64);
    }
    if (threadIdx.x == 0) {
        const double d = sd / sc;
        ws2[j] = d * d;
    }
}

__global__ __launch_bounds__(64) void dvh_out_kernel(
    const double* __restrict__ ws2, float* __restrict__ out)
{
    double v = (threadIdx.x < NB * NK) ? ws2[threadIdx.x] : 0.0;
    #pragma unroll
    for (int off = 32; off > 0; off >>= 1)
        v += __shfl_down(v, off, 64);
    if (threadIdx.x == 0) out[0] = (float)(v / (double)(NB * NK));
}

extern "C" void kernel_launch(void* const* d_in, const int* in_sizes, int n_in,
                              void* d_out, int out_size, void* d_ws, size_t ws_size,
                              hipStream_t stream) {
    const float* pred = (const float*)d_in[0];
    const float* targ = (const float*)d_in[1];
    const int*   mask = (const int*)d_in[2];
    const float* ptv  = (const float*)d_in[3];
    float* out = (float*)d_out;
    double* ws  = (double*)d_ws;
    double* ws2 = ws + WS_PARTIALS;

    dvh_sum_kernel<<<NBLOCKS, BLOCK, 0, stream>>>(pred, targ, mask, ptv, ws);
    dvh_reduce_kernel<<<NB * NK, 64, 0, stream>>>(ws, ws2);
    dvh_out_kernel<<<1, 64, 0, stream>>>(ws2, out);
}